// Round 25
// baseline (114.257 us; speedup 1.0000x reference)
//
#include <hip/hip_runtime.h>
#include <hip/hip_bf16.h>
#include <math.h>
#include <limits.h>

#define Bb 32
#define Tt 16384
#define Cc 128
#define Dd 256
#define Pp 2048
#define GMAX 4096
#define TP 16

typedef __attribute__((ext_vector_type(8))) short bf16x8;
typedef __attribute__((ext_vector_type(4))) float f32x4;

// float -> bf16 (RNE)
__device__ __forceinline__ unsigned short f2bf(float f) {
  unsigned u = __float_as_uint(f);
  return (unsigned short)((u + 0x7FFFu + ((u >> 16) & 1u)) >> 16);
}

// pid as XLA-jit computes it: divide(t,7) -> multiply(t, fl(1/7)).
// fl(1/7) = 0x3E124925. VERIFIED passing combination (R19) — do not touch.
__device__ __forceinline__ int PID(float t) {
  return (int)floorf(t * 0.14285714924335479736328125f);
}

// ---------------- Kernel A: radix-16 cumsum (blocks 0..31) + W pack (32..47) --
// Scan part is the VERIFIED producer replica (R19). packw folded in to drop a
// launch and overlap with the scan (independent work).
__global__ __launch_bounds__(256) void scan_k(const float* __restrict__ td,
                                              int* __restrict__ starts,
                                              int* __restrict__ ngroups,
                                              const float* __restrict__ Wm,
                                              unsigned short* __restrict__ Wp) {
  if (blockIdx.x >= Bb) {              // ---- packw role ----
    const int t = (blockIdx.x - Bb) * 256 + threadIdx.x;
    const int tile = t >> 6, lane = t & 63;
    const int nt = tile >> 2, kt = tile & 3;
    const int kbase = kt * 32 + (lane >> 4) * 8;
    const int n = nt * 16 + (lane & 15);
    unsigned short tmp[8];
    #pragma unroll
    for (int j = 0; j < 8; ++j)
      tmp[j] = f2bf(Wm[(size_t)(kbase + j) * Dd + n]);
    *(uint4*)(Wp + (size_t)tile * 512 + lane * 8) = *(const uint4*)tmp;
    return;
  }

  __shared__ float buf[Tt];
  __shared__ float S0[1024], P0[1024];
  __shared__ float S1[64],  P1[64];
  __shared__ float P2s[4];
  __shared__ int   cnt[256];

  const int b = blockIdx.x;
  const int tid = threadIdx.x;
  const float* row = td + (size_t)b * Tt;

  const float4* r4 = (const float4*)row;
  float4* b4 = (float4*)buf;
  for (int i = tid; i < Tt / 4; i += 256) b4[i] = r4[i];
  __syncthreads();

  for (int k = tid; k < 1024; k += 256) {
    const float* p = buf + k * 16;
    float s = p[0];
    #pragma unroll
    for (int j = 1; j < 16; ++j) s += p[j];
    S0[k] = s;
  }
  __syncthreads();

  if (tid < 64) {
    const float* p = S0 + tid * 16;
    float s = p[0];
    #pragma unroll
    for (int j = 1; j < 16; ++j) s += p[j];
    S1[tid] = s;
  }
  __syncthreads();

  if (tid == 0) {
    float run = 0.f;
    for (int m = 0; m < 4; ++m) {
      const float* p = S1 + m * 16;
      float s = p[0];
      #pragma unroll
      for (int j = 1; j < 16; ++j) s += p[j];
      run = (m == 0) ? s : run + s;
      P2s[m] = run;
    }
  }
  __syncthreads();

  if (tid < 64) {
    const int k2 = tid >> 4, j1 = tid & 15;
    const float* p = S1 + (k2 << 4);
    float s = p[0];
    for (int j = 1; j <= j1; ++j) s += p[j];
    P1[tid] = (k2 == 0) ? s : s + P2s[k2 - 1];
  }
  __syncthreads();

  for (int k = tid; k < 1024; k += 256) {
    const int k1 = k >> 4, j = k & 15;
    const float* p = S0 + (k1 << 4);
    float s = p[0];
    for (int jj = 1; jj <= j; ++jj) s += p[jj];
    P0[k] = (k1 == 0) ? s : s + P1[k1 - 1];
  }
  __syncthreads();

  int pprev0;
  if (tid == 0) pprev0 = INT_MIN;
  else {
    const int k = 4 * tid - 1;
    const float t = (k == 0) ? S0[0] : S0[k] + P0[k - 1];
    pprev0 = PID(t);
  }

  int pprev = pprev0, count = 0;
  for (int tk = 0; tk < 4; ++tk) {
    const int k = 4 * tid + tk;
    const float carry = (k == 0) ? 0.f : P0[k - 1];
    const float* p = buf + k * 16;
    float s = 0.f;
    #pragma unroll
    for (int j = 0; j < 16; ++j) {
      s = (j == 0) ? p[0] : s + p[j];
      const float t = (k == 0) ? s : s + carry;
      const int pid = PID(t);
      count += (pid != pprev);
      pprev = pid;
    }
  }
  cnt[tid] = count;
  __syncthreads();
  if (tid == 0) {
    int run = 0;
    for (int k = 0; k < 256; ++k) { int c = cnt[k]; cnt[k] = run; run += c; }
  }
  __syncthreads();

  int r = cnt[tid];
  pprev = pprev0;
  int* stb = starts + b * GMAX;
  for (int tk = 0; tk < 4; ++tk) {
    const int k = 4 * tid + tk;
    const float carry = (k == 0) ? 0.f : P0[k - 1];
    const float* p = buf + k * 16;
    float s = 0.f;
    #pragma unroll
    for (int j = 0; j < 16; ++j) {
      s = (j == 0) ? p[0] : s + p[j];
      const float t = (k == 0) ? s : s + carry;
      const int pid = PID(t);
      if (pid != pprev) stb[r++] = k * 16 + j;
      pprev = pid;
    }
  }
  if (tid == 255) {
    ngroups[b] = r;
    stb[r] = Tt;
  }
}

// ---------------- Kernel B1: group means, persistent waves --------------------
// 2048 blocks x 4 waves = 8192 waves = exactly 32/CU, zero tail. Each wave
// processes 8 ADJACENT patch slots sequentially (contiguous ~112 rows -> L2
// locality; boundary loads amortized). Inner body identical to R24 (proven).
__global__ __launch_bounds__(256) void means_k(const float* __restrict__ x,
                                               const int* __restrict__ starts,
                                               const int* __restrict__ ngroups,
                                               unsigned short* __restrict__ means) {
  const int wv = blockIdx.x * 4 + (threadIdx.x >> 6);   // 0..8191
  const int lane = threadIdx.x & 63;
  const int pbase = wv * 8;            // global slot base; stays within one b
  const int b = pbase >> 11;
  const int p0 = pbase & (Pp - 1);
  const int ng = ngroups[b];
  const int off = Pp - ng;
  const int r2 = lane >> 5;
  const int cq = lane & 31;
  const int* st = starts + b * GMAX;
  const float* xb = x + ((size_t)b * Tt) * Cc + 4 * cq;

  for (int k = 0; k < 8; ++k) {
    const int p = p0 + k;
    const int g = p - off;
    unsigned short* mp = means + ((size_t)b * Pp + p) * Cc;
    if (g < 0) {
      *(unsigned int*)(mp + 2 * lane) = 0u;
      continue;
    }
    const int s = st[g], e = st[g + 1];
    const int n = e - s;

    const float* xp = xb + (size_t)s * Cc;
    float4 a0 = make_float4(0.f, 0.f, 0.f, 0.f);
    float4 a1 = make_float4(0.f, 0.f, 0.f, 0.f);
    int i = r2;
    for (; i + 2 < n; i += 4) {
      const float4 v0 = *(const float4*)(xp + (size_t)i * Cc);
      const float4 v1 = *(const float4*)(xp + (size_t)(i + 2) * Cc);
      a0.x += v0.x; a0.y += v0.y; a0.z += v0.z; a0.w += v0.w;
      a1.x += v1.x; a1.y += v1.y; a1.z += v1.z; a1.w += v1.w;
    }
    if (i < n) {
      const float4 v = *(const float4*)(xp + (size_t)i * Cc);
      a0.x += v.x; a0.y += v.y; a0.z += v.z; a0.w += v.w;
    }
    a0.x += a1.x; a0.y += a1.y; a0.z += a1.z; a0.w += a1.w;
    a0.x += __shfl_xor(a0.x, 32);
    a0.y += __shfl_xor(a0.y, 32);
    a0.z += __shfl_xor(a0.z, 32);
    a0.w += __shfl_xor(a0.w, 32);
    if (r2 == 0) {
      const float fn = (float)n;
      unsigned short q[4];
      q[0] = f2bf(a0.x / fn); q[1] = f2bf(a0.y / fn);
      q[2] = f2bf(a0.z / fn); q[3] = f2bf(a0.w / fn);
      *(uint2*)(mp + 4 * cq) = *(const uint2*)q;
    }
  }
}

// ---------------- Kernel B2: MFMA projection out = means*W + b ----------------
// Unchanged from R24 (verified, fast).
__global__ __launch_bounds__(256) void gemm_k(const unsigned short* __restrict__ means,
                                              const unsigned short* __restrict__ Wp,
                                              const float* __restrict__ bias,
                                              const int* __restrict__ ngroups,
                                              float* __restrict__ out_patches,
                                              float* __restrict__ out_valid) {
  const int blk = blockIdx.x;
  const int b = blk >> 7;
  const int pt = (blk & 127) * TP;
  const int tid = threadIdx.x;
  const int ng = ngroups[b];
  const int off = Pp - ng;

  if (tid < TP)
    out_valid[(size_t)b * Pp + pt + tid] = (pt + tid >= off) ? 1.0f : 0.0f;

  if (pt + TP <= off) {
    const float bias_v = bias[tid];
    const size_t obase = ((size_t)b * Pp + pt) * Dd + tid;
    #pragma unroll
    for (int j = 0; j < TP; ++j) out_patches[obase + (size_t)j * Dd] = bias_v;
    return;
  }

  __shared__ unsigned short alds[TP * Cc];
  {
    const int row = tid >> 4, seg = tid & 15;
    const uint4 v = *(const uint4*)(means + ((size_t)(b * Pp + pt + row)) * Cc + seg * 8);
    *(uint4*)((char*)alds + row * 256 + ((seg * 16) ^ ((row & 7) << 4))) = v;
  }
  __syncthreads();

  const int w = tid >> 6, l = tid & 63;
  const int mrow = l & 15;

  bf16x8 a[4];
  #pragma unroll
  for (int kt = 0; kt < 4; ++kt) {
    const int boff = ((kt * 4 + (l >> 4)) * 16) ^ ((mrow & 7) << 4);
    a[kt] = *(const bf16x8*)((const char*)alds + mrow * 256 + boff);
  }

  f32x4 acc[4];
  #pragma unroll
  for (int nt4 = 0; nt4 < 4; ++nt4) acc[nt4] = (f32x4){0.f, 0.f, 0.f, 0.f};

  #pragma unroll
  for (int nt4 = 0; nt4 < 4; ++nt4) {
    const int nt = w * 4 + nt4;
    #pragma unroll
    for (int kt = 0; kt < 4; ++kt) {
      const bf16x8 bf = *(const bf16x8*)(Wp + (size_t)(nt * 4 + kt) * 512 + l * 8);
      acc[nt4] = __builtin_amdgcn_mfma_f32_16x16x32_bf16(a[kt], bf, acc[nt4], 0, 0, 0);
    }
  }

  #pragma unroll
  for (int nt4 = 0; nt4 < 4; ++nt4) {
    const int d = (w * 4 + nt4) * 16 + mrow;
    const float bv = bias[d];
    const size_t ob = ((size_t)b * Pp + pt + (l >> 4) * 4) * Dd + d;
    #pragma unroll
    for (int j = 0; j < 4; ++j)
      out_patches[ob + (size_t)j * Dd] = acc[nt4][j] + bv;
  }
}

extern "C" void kernel_launch(void* const* d_in, const int* in_sizes, int n_in,
                              void* d_out, int out_size, void* d_ws, size_t ws_size,
                              hipStream_t stream) {
  const float* x    = (const float*)d_in[0];
  const float* td   = (const float*)d_in[1];
  const float* Wm   = (const float*)d_in[2];
  const float* bias = (const float*)d_in[3];
  float* out = (float*)d_out;

  int*            starts  = (int*)d_ws;                                  // 512 KB
  int*            ngroups = (int*)((char*)d_ws + 524288);                // 128 B
  unsigned short* means   = (unsigned short*)((char*)d_ws + (1 << 20));  // 16.8 MB
  unsigned short* Wp      = (unsigned short*)((char*)d_ws + (20 << 20)); // 64 KB

  scan_k<<<Bb + 16, 256, 0, stream>>>(td, starts, ngroups, Wm, Wp);
  means_k<<<2048, 256, 0, stream>>>(x, starts, ngroups, means);
  gemm_k<<<Bb * (Pp / TP), 256, 0, stream>>>(means, Wp, bias, ngroups,
                                             out, out + (size_t)Bb * Pp * Dd);
}

// Round 26
// 102.717 us; speedup vs baseline: 1.1123x; 1.1123x over previous
//
#include <hip/hip_runtime.h>
#include <hip/hip_bf16.h>
#include <math.h>
#include <limits.h>

#define Bb 32
#define Tt 16384
#define Cc 128
#define Dd 256
#define Pp 2048
#define GMAX 4096
#define TP 16

typedef __attribute__((ext_vector_type(8))) short bf16x8;
typedef __attribute__((ext_vector_type(4))) float f32x4;

// float -> bf16 (RNE)
__device__ __forceinline__ unsigned short f2bf(float f) {
  unsigned u = __float_as_uint(f);
  return (unsigned short)((u + 0x7FFFu + ((u >> 16) & 1u)) >> 16);
}

// pid as XLA-jit computes it: divide(t,7) -> multiply(t, fl(1/7)).
// fl(1/7) = 0x3E124925. VERIFIED passing combination (R19) — do not touch.
__device__ __forceinline__ int PID(float t) {
  return (int)floorf(t * 0.14285714924335479736328125f);
}

// ---------------- Kernel A: radix-16 cumsum (blocks 0..31) + W pack (32..47) --
// Scan part is the VERIFIED producer replica (R19). packw folded in (R25).
__global__ __launch_bounds__(256) void scan_k(const float* __restrict__ td,
                                              int* __restrict__ starts,
                                              int* __restrict__ ngroups,
                                              const float* __restrict__ Wm,
                                              unsigned short* __restrict__ Wp) {
  if (blockIdx.x >= Bb) {              // ---- packw role ----
    const int t = (blockIdx.x - Bb) * 256 + threadIdx.x;
    const int tile = t >> 6, lane = t & 63;
    const int nt = tile >> 2, kt = tile & 3;
    const int kbase = kt * 32 + (lane >> 4) * 8;
    const int n = nt * 16 + (lane & 15);
    unsigned short tmp[8];
    #pragma unroll
    for (int j = 0; j < 8; ++j)
      tmp[j] = f2bf(Wm[(size_t)(kbase + j) * Dd + n]);
    *(uint4*)(Wp + (size_t)tile * 512 + lane * 8) = *(const uint4*)tmp;
    return;
  }

  __shared__ float buf[Tt];
  __shared__ float S0[1024], P0[1024];
  __shared__ float S1[64],  P1[64];
  __shared__ float P2s[4];
  __shared__ int   cnt[256];

  const int b = blockIdx.x;
  const int tid = threadIdx.x;
  const float* row = td + (size_t)b * Tt;

  const float4* r4 = (const float4*)row;
  float4* b4 = (float4*)buf;
  for (int i = tid; i < Tt / 4; i += 256) b4[i] = r4[i];
  __syncthreads();

  for (int k = tid; k < 1024; k += 256) {
    const float* p = buf + k * 16;
    float s = p[0];
    #pragma unroll
    for (int j = 1; j < 16; ++j) s += p[j];
    S0[k] = s;
  }
  __syncthreads();

  if (tid < 64) {
    const float* p = S0 + tid * 16;
    float s = p[0];
    #pragma unroll
    for (int j = 1; j < 16; ++j) s += p[j];
    S1[tid] = s;
  }
  __syncthreads();

  if (tid == 0) {
    float run = 0.f;
    for (int m = 0; m < 4; ++m) {
      const float* p = S1 + m * 16;
      float s = p[0];
      #pragma unroll
      for (int j = 1; j < 16; ++j) s += p[j];
      run = (m == 0) ? s : run + s;
      P2s[m] = run;
    }
  }
  __syncthreads();

  if (tid < 64) {
    const int k2 = tid >> 4, j1 = tid & 15;
    const float* p = S1 + (k2 << 4);
    float s = p[0];
    for (int j = 1; j <= j1; ++j) s += p[j];
    P1[tid] = (k2 == 0) ? s : s + P2s[k2 - 1];
  }
  __syncthreads();

  for (int k = tid; k < 1024; k += 256) {
    const int k1 = k >> 4, j = k & 15;
    const float* p = S0 + (k1 << 4);
    float s = p[0];
    for (int jj = 1; jj <= j; ++jj) s += p[jj];
    P0[k] = (k1 == 0) ? s : s + P1[k1 - 1];
  }
  __syncthreads();

  int pprev0;
  if (tid == 0) pprev0 = INT_MIN;
  else {
    const int k = 4 * tid - 1;
    const float t = (k == 0) ? S0[0] : S0[k] + P0[k - 1];
    pprev0 = PID(t);
  }

  int pprev = pprev0, count = 0;
  for (int tk = 0; tk < 4; ++tk) {
    const int k = 4 * tid + tk;
    const float carry = (k == 0) ? 0.f : P0[k - 1];
    const float* p = buf + k * 16;
    float s = 0.f;
    #pragma unroll
    for (int j = 0; j < 16; ++j) {
      s = (j == 0) ? p[0] : s + p[j];
      const float t = (k == 0) ? s : s + carry;
      const int pid = PID(t);
      count += (pid != pprev);
      pprev = pid;
    }
  }
  cnt[tid] = count;
  __syncthreads();
  if (tid == 0) {
    int run = 0;
    for (int k = 0; k < 256; ++k) { int c = cnt[k]; cnt[k] = run; run += c; }
  }
  __syncthreads();

  int r = cnt[tid];
  pprev = pprev0;
  int* stb = starts + b * GMAX;
  for (int tk = 0; tk < 4; ++tk) {
    const int k = 4 * tid + tk;
    const float carry = (k == 0) ? 0.f : P0[k - 1];
    const float* p = buf + k * 16;
    float s = 0.f;
    #pragma unroll
    for (int j = 0; j < 16; ++j) {
      s = (j == 0) ? p[0] : s + p[j];
      const float t = (k == 0) ? s : s + carry;
      const int pid = PID(t);
      if (pid != pprev) stb[r++] = k * 16 + j;
      pprev = pid;
    }
  }
  if (tid == 255) {
    ngroups[b] = r;
    stb[r] = Tt;
  }
}

// ---------------- Kernel B1: group means — R24 semantics, full occupancy ------
// 256-thread blocks, 4 waves, ONE patch slot per wave (identical per-wave work
// to R24's fastest version), but 8 blocks/CU x 4 waves = 32 waves/CU (R24's
// 64-thread blocks capped at ~16 blocks/CU = half occupancy).
__global__ __launch_bounds__(256) void means_k(const float* __restrict__ x,
                                               const int* __restrict__ starts,
                                               const int* __restrict__ ngroups,
                                               unsigned short* __restrict__ means) {
  const int slot = blockIdx.x * 4 + (threadIdx.x >> 6);  // 0..65535
  const int lane = threadIdx.x & 63;
  const int b = slot >> 11;
  const int p = slot & (Pp - 1);
  const int ng = ngroups[b];
  const int off = Pp - ng;
  const int g = p - off;
  unsigned short* mp = means + ((size_t)b * Pp + p) * Cc;

  if (g < 0) {                         // padding slot -> zero mean
    *(unsigned int*)(mp + 2 * lane) = 0u;
    return;
  }

  const int* st = starts + b * GMAX;
  const int s = st[g], e = st[g + 1];
  const int n = e - s;
  const int r2 = lane >> 5;
  const int cq = lane & 31;

  const float* xp = x + ((size_t)b * Tt + s) * Cc + 4 * cq;
  float4 a0 = make_float4(0.f, 0.f, 0.f, 0.f);
  float4 a1 = make_float4(0.f, 0.f, 0.f, 0.f);
  int i = r2;
  for (; i + 2 < n; i += 4) {
    const float4 v0 = *(const float4*)(xp + (size_t)i * Cc);
    const float4 v1 = *(const float4*)(xp + (size_t)(i + 2) * Cc);
    a0.x += v0.x; a0.y += v0.y; a0.z += v0.z; a0.w += v0.w;
    a1.x += v1.x; a1.y += v1.y; a1.z += v1.z; a1.w += v1.w;
  }
  if (i < n) {
    const float4 v = *(const float4*)(xp + (size_t)i * Cc);
    a0.x += v.x; a0.y += v.y; a0.z += v.z; a0.w += v.w;
  }
  a0.x += a1.x; a0.y += a1.y; a0.z += a1.z; a0.w += a1.w;
  a0.x += __shfl_xor(a0.x, 32);
  a0.y += __shfl_xor(a0.y, 32);
  a0.z += __shfl_xor(a0.z, 32);
  a0.w += __shfl_xor(a0.w, 32);
  if (r2 == 0) {
    const float fn = (float)n;
    unsigned short q[4];
    q[0] = f2bf(a0.x / fn); q[1] = f2bf(a0.y / fn);
    q[2] = f2bf(a0.z / fn); q[3] = f2bf(a0.w / fn);
    *(uint2*)(mp + 4 * cq) = *(const uint2*)q;
  }
}

// ---------------- Kernel B2: MFMA projection out = means*W + b ----------------
// Unchanged from R24 (verified, fast).
__global__ __launch_bounds__(256) void gemm_k(const unsigned short* __restrict__ means,
                                              const unsigned short* __restrict__ Wp,
                                              const float* __restrict__ bias,
                                              const int* __restrict__ ngroups,
                                              float* __restrict__ out_patches,
                                              float* __restrict__ out_valid) {
  const int blk = blockIdx.x;
  const int b = blk >> 7;
  const int pt = (blk & 127) * TP;
  const int tid = threadIdx.x;
  const int ng = ngroups[b];
  const int off = Pp - ng;

  if (tid < TP)
    out_valid[(size_t)b * Pp + pt + tid] = (pt + tid >= off) ? 1.0f : 0.0f;

  if (pt + TP <= off) {
    const float bias_v = bias[tid];
    const size_t obase = ((size_t)b * Pp + pt) * Dd + tid;
    #pragma unroll
    for (int j = 0; j < TP; ++j) out_patches[obase + (size_t)j * Dd] = bias_v;
    return;
  }

  __shared__ unsigned short alds[TP * Cc];
  {
    const int row = tid >> 4, seg = tid & 15;
    const uint4 v = *(const uint4*)(means + ((size_t)(b * Pp + pt + row)) * Cc + seg * 8);
    *(uint4*)((char*)alds + row * 256 + ((seg * 16) ^ ((row & 7) << 4))) = v;
  }
  __syncthreads();

  const int w = tid >> 6, l = tid & 63;
  const int mrow = l & 15;

  bf16x8 a[4];
  #pragma unroll
  for (int kt = 0; kt < 4; ++kt) {
    const int boff = ((kt * 4 + (l >> 4)) * 16) ^ ((mrow & 7) << 4);
    a[kt] = *(const bf16x8*)((const char*)alds + mrow * 256 + boff);
  }

  f32x4 acc[4];
  #pragma unroll
  for (int nt4 = 0; nt4 < 4; ++nt4) acc[nt4] = (f32x4){0.f, 0.f, 0.f, 0.f};

  #pragma unroll
  for (int nt4 = 0; nt4 < 4; ++nt4) {
    const int nt = w * 4 + nt4;
    #pragma unroll
    for (int kt = 0; kt < 4; ++kt) {
      const bf16x8 bf = *(const bf16x8*)(Wp + (size_t)(nt * 4 + kt) * 512 + l * 8);
      acc[nt4] = __builtin_amdgcn_mfma_f32_16x16x32_bf16(a[kt], bf, acc[nt4], 0, 0, 0);
    }
  }

  #pragma unroll
  for (int nt4 = 0; nt4 < 4; ++nt4) {
    const int d = (w * 4 + nt4) * 16 + mrow;
    const float bv = bias[d];
    const size_t ob = ((size_t)b * Pp + pt + (l >> 4) * 4) * Dd + d;
    #pragma unroll
    for (int j = 0; j < 4; ++j)
      out_patches[ob + (size_t)j * Dd] = acc[nt4][j] + bv;
  }
}

extern "C" void kernel_launch(void* const* d_in, const int* in_sizes, int n_in,
                              void* d_out, int out_size, void* d_ws, size_t ws_size,
                              hipStream_t stream) {
  const float* x    = (const float*)d_in[0];
  const float* td   = (const float*)d_in[1];
  const float* Wm   = (const float*)d_in[2];
  const float* bias = (const float*)d_in[3];
  float* out = (float*)d_out;

  int*            starts  = (int*)d_ws;                                  // 512 KB
  int*            ngroups = (int*)((char*)d_ws + 524288);                // 128 B
  unsigned short* means   = (unsigned short*)((char*)d_ws + (1 << 20));  // 16.8 MB
  unsigned short* Wp      = (unsigned short*)((char*)d_ws + (20 << 20)); // 64 KB

  scan_k<<<Bb + 16, 256, 0, stream>>>(td, starts, ngroups, Wm, Wp);
  means_k<<<Bb * Pp / 4, 256, 0, stream>>>(x, starts, ngroups, means);
  gemm_k<<<Bb * (Pp / TP), 256, 0, stream>>>(means, Wp, bias, ngroups,
                                             out, out + (size_t)Bb * Pp * Dd);
}